// Round 1
// baseline (382.616 us; speedup 1.0000x reference)
//
#include <hip/hip_runtime.h>
#include <math.h>

#define BN_EPS 1e-5f

// ---------------------------------------------------------------------------
// Kernel P: posm[c] = mean over 64x64 of bilinear-upsampled pos_embed[c].
// Bilinear (half-pixel centers, jax renormalized edges == clamped indices)
// is separable: posm[c] = sum_{p,q} (W[p]/64)(W[q]/64) * pos[c,p,q],
// W[p] = column sums of the 7->64 weight matrix. One block, one thread per c.
// ---------------------------------------------------------------------------
__global__ __launch_bounds__(512) void pos_mean_kernel(
    const float* __restrict__ pos, float* __restrict__ posm)
{
    const int c = threadIdx.x;  // 0..511
    float W[7] = {0.f, 0.f, 0.f, 0.f, 0.f, 0.f, 0.f};
    for (int i = 0; i < 64; ++i) {
        float src = (i + 0.5f) * (7.0f / 64.0f) - 0.5f;
        float fl  = floorf(src);
        int   i0  = (int)fl;
        float f   = src - fl;
        int p0 = i0 < 0 ? 0 : (i0 > 6 ? 6 : i0);
        int i1 = i0 + 1;
        int p1 = i1 < 0 ? 0 : (i1 > 6 ? 6 : i1);
        W[p0] += 1.f - f;
        W[p1] += f;
    }
    float acc = 0.f;
    for (int p = 0; p < 7; ++p) {
        for (int q = 0; q < 7; ++q) {
            acc += W[p] * W[q] * pos[c * 49 + p * 7 + q];
        }
    }
    posm[c] = acc * (1.0f / 4096.0f);
}

// ---------------------------------------------------------------------------
// Kernel A: pooled[b*512+c] = mean(x[b,c,:,:]) + posm[c].
// One wave per (b,c) row of 4096 contiguous floats (16 KiB).
// 64 lanes x 16 float4 coalesced loads, shfl-xor wave reduction.
// This kernel is the HBM-roofline cost (256 MiB read).
// ---------------------------------------------------------------------------
__global__ __launch_bounds__(256) void pool_kernel(
    const float* __restrict__ x, const float* __restrict__ posm,
    float* __restrict__ pooled)
{
    const int row  = (int)((blockIdx.x * blockDim.x + threadIdx.x) >> 6); // 0..16383
    const int lane = threadIdx.x & 63;
    const int c    = row & 511;

    const float4* xr = reinterpret_cast<const float4*>(x) + (size_t)row * 1024;
    float sum = 0.f;
#pragma unroll
    for (int j = 0; j < 16; ++j) {
        float4 v = xr[j * 64 + lane];
        sum += v.x + v.y + v.z + v.w;
    }
#pragma unroll
    for (int off = 32; off > 0; off >>= 1)
        sum += __shfl_xor(sum, off, 64);

    if (lane == 0)
        pooled[row] = sum * (1.0f / 4096.0f) + posm[c];
}

// ---------------------------------------------------------------------------
// Kernel B: y[b,o] = relu(BN(dot(pooled[b,:], conv_w[o,:]) + conv_b[o])).
// One wave per (b,o) output; 512-long dot via 2x float4 per lane.
// conv_w (1 MiB) is L2-resident across its 32 logical re-reads.
// ---------------------------------------------------------------------------
__global__ __launch_bounds__(256) void matmul_bn_kernel(
    const float* __restrict__ pooled, const float* __restrict__ conv_w,
    const float* __restrict__ conv_b,
    const float* __restrict__ bn_gamma, const float* __restrict__ bn_beta,
    const float* __restrict__ bn_mean,  const float* __restrict__ bn_var,
    float* __restrict__ out)
{
    const int wid  = (int)((blockIdx.x * blockDim.x + threadIdx.x) >> 6); // 0..16383
    const int lane = threadIdx.x & 63;
    const int b    = wid >> 9;
    const int o    = wid & 511;

    const float4* pr = reinterpret_cast<const float4*>(pooled) + b * 128;
    const float4* wr = reinterpret_cast<const float4*>(conv_w) + o * 128;

    float sum = 0.f;
#pragma unroll
    for (int j = 0; j < 2; ++j) {
        float4 p4 = pr[j * 64 + lane];
        float4 w4 = wr[j * 64 + lane];
        sum += p4.x * w4.x + p4.y * w4.y + p4.z * w4.z + p4.w * w4.w;
    }
#pragma unroll
    for (int off = 32; off > 0; off >>= 1)
        sum += __shfl_xor(sum, off, 64);

    if (lane == 0) {
        float y = sum + conv_b[o];
        y = bn_gamma[o] * (y - bn_mean[o]) * rsqrtf(bn_var[o] + BN_EPS) + bn_beta[o];
        out[wid] = y > 0.f ? y : 0.f;
    }
}

extern "C" void kernel_launch(void* const* d_in, const int* in_sizes, int n_in,
                              void* d_out, int out_size, void* d_ws, size_t ws_size,
                              hipStream_t stream) {
    const float* x        = (const float*)d_in[0];   // (32,512,64,64)
    const float* pos      = (const float*)d_in[1];   // (1,512,7,7)
    const float* conv_w   = (const float*)d_in[2];   // (512,512)
    const float* conv_b   = (const float*)d_in[3];   // (512,)
    const float* bn_gamma = (const float*)d_in[4];
    const float* bn_beta  = (const float*)d_in[5];
    const float* bn_mean  = (const float*)d_in[6];
    const float* bn_var   = (const float*)d_in[7];
    float* out = (float*)d_out;                      // (32,512,1,1) fp32

    float* posm   = (float*)d_ws;          // 512 floats
    float* pooled = posm + 512;            // 16384 floats (offset 2 KiB, 16B-aligned)

    pos_mean_kernel<<<1, 512, 0, stream>>>(pos, posm);
    pool_kernel<<<4096, 256, 0, stream>>>(x, posm, pooled);
    matmul_bn_kernel<<<4096, 256, 0, stream>>>(pooled, conv_w, conv_b,
                                               bn_gamma, bn_beta, bn_mean, bn_var,
                                               out);
}

// Round 2
// 360.761 us; speedup vs baseline: 1.0606x; 1.0606x over previous
//
#include <hip/hip_runtime.h>
#include <math.h>

#define BN_EPS 1e-5f

typedef float f4 __attribute__((ext_vector_type(4)));

// ---------------------------------------------------------------------------
// Kernel P: posm[c] = mean over 64x64 of bilinear-upsampled pos_embed[c].
// Separable: posm[c] = sum_{p,q} (W[p]/64)(W[q]/64) * pos[c,p,q], where W[p]
// are column sums of the 7->64 half-pixel bilinear weight matrix (jax's
// renormalized edges == clamped indices). One block, one thread per c.
// ---------------------------------------------------------------------------
__global__ __launch_bounds__(512) void pos_mean_kernel(
    const float* __restrict__ pos, float* __restrict__ posm)
{
    const int c = threadIdx.x;  // 0..511
    float W[7] = {0.f, 0.f, 0.f, 0.f, 0.f, 0.f, 0.f};
    for (int i = 0; i < 64; ++i) {
        float src = (i + 0.5f) * (7.0f / 64.0f) - 0.5f;
        float fl  = floorf(src);
        int   i0  = (int)fl;
        float f   = src - fl;
        int p0 = i0 < 0 ? 0 : (i0 > 6 ? 6 : i0);
        int i1 = i0 + 1;
        int p1 = i1 < 0 ? 0 : (i1 > 6 ? 6 : i1);
        W[p0] += 1.f - f;
        W[p1] += f;
    }
    float acc = 0.f;
    for (int p = 0; p < 7; ++p)
        for (int q = 0; q < 7; ++q)
            acc += W[p] * W[q] * pos[c * 49 + p * 7 + q];
    posm[c] = acc * (1.0f / 4096.0f);
}

// ---------------------------------------------------------------------------
// Kernel A: pooled[b*512+c] = mean(x[b,c,:,:]) + posm[c].
// One wave per (b,c) row (16 KiB contiguous). 64 lanes x 16 float4 NT loads
// (x is pure streaming, zero reuse -> bypass L2 with the nt flag), shfl-xor
// wave reduction. This kernel IS the HBM roofline cost (268 MB read).
// ---------------------------------------------------------------------------
__global__ __launch_bounds__(256) void pool_kernel(
    const float* __restrict__ x, const float* __restrict__ posm,
    float* __restrict__ pooled)
{
    const int row  = (int)((blockIdx.x * blockDim.x + threadIdx.x) >> 6); // 0..16383
    const int lane = threadIdx.x & 63;
    const int c    = row & 511;

    const f4* xr = reinterpret_cast<const f4*>(x) + (size_t)row * 1024;
    float sum = 0.f;
#pragma unroll
    for (int j = 0; j < 16; ++j) {
        f4 v = __builtin_nontemporal_load(xr + j * 64 + lane);
        sum += (v.x + v.y) + (v.z + v.w);
    }
#pragma unroll
    for (int off = 32; off > 0; off >>= 1)
        sum += __shfl_xor(sum, off, 64);

    if (lane == 0)
        pooled[row] = sum * (1.0f / 4096.0f) + posm[c];
}

// ---------------------------------------------------------------------------
// Kernel B: y[b,o] = relu(BN(dot(pooled[b,:], conv_w[o,:]) + conv_b[o])).
// One wave per (b, o-pair): the pooled fragment is loaded once per lane and
// reused for two conv_w rows -> half the waves of one-output-per-wave.
// conv_w (1 MiB, 32x reuse across b) stays on the cached path (no NT).
// ---------------------------------------------------------------------------
__global__ __launch_bounds__(256) void matmul_bn_kernel(
    const float* __restrict__ pooled, const float* __restrict__ conv_w,
    const float* __restrict__ conv_b,
    const float* __restrict__ bn_gamma, const float* __restrict__ bn_beta,
    const float* __restrict__ bn_mean,  const float* __restrict__ bn_var,
    float* __restrict__ out)
{
    const int wid  = (int)((blockIdx.x * blockDim.x + threadIdx.x) >> 6); // 0..8191
    const int lane = threadIdx.x & 63;
    const int b    = wid >> 8;          // 0..31
    const int o0   = (wid & 255) * 2;   // even output index
    const int o1   = o0 + 1;

    const f4* pr = reinterpret_cast<const f4*>(pooled) + b * 128;
    const f4* w0 = reinterpret_cast<const f4*>(conv_w) + o0 * 128;
    const f4* w1 = reinterpret_cast<const f4*>(conv_w) + o1 * 128;

    float s0 = 0.f, s1 = 0.f;
#pragma unroll
    for (int j = 0; j < 2; ++j) {
        f4 p4 = pr[j * 64 + lane];
        f4 a4 = w0[j * 64 + lane];
        f4 b4 = w1[j * 64 + lane];
        s0 += p4.x * a4.x + p4.y * a4.y + p4.z * a4.z + p4.w * a4.w;
        s1 += p4.x * b4.x + p4.y * b4.y + p4.z * b4.z + p4.w * b4.w;
    }
#pragma unroll
    for (int off = 32; off > 0; off >>= 1) {
        s0 += __shfl_xor(s0, off, 64);
        s1 += __shfl_xor(s1, off, 64);
    }

    if (lane == 0) {
        float y0 = s0 + conv_b[o0];
        y0 = bn_gamma[o0] * (y0 - bn_mean[o0]) * rsqrtf(bn_var[o0] + BN_EPS) + bn_beta[o0];
        float y1 = s1 + conv_b[o1];
        y1 = bn_gamma[o1] * (y1 - bn_mean[o1]) * rsqrtf(bn_var[o1] + BN_EPS) + bn_beta[o1];
        const int base = b * 512 + o0;
        out[base]     = y0 > 0.f ? y0 : 0.f;
        out[base + 1] = y1 > 0.f ? y1 : 0.f;
    }
}

extern "C" void kernel_launch(void* const* d_in, const int* in_sizes, int n_in,
                              void* d_out, int out_size, void* d_ws, size_t ws_size,
                              hipStream_t stream) {
    const float* x        = (const float*)d_in[0];   // (32,512,64,64)
    const float* pos      = (const float*)d_in[1];   // (1,512,7,7)
    const float* conv_w   = (const float*)d_in[2];   // (512,512)
    const float* conv_b   = (const float*)d_in[3];   // (512,)
    const float* bn_gamma = (const float*)d_in[4];
    const float* bn_beta  = (const float*)d_in[5];
    const float* bn_mean  = (const float*)d_in[6];
    const float* bn_var   = (const float*)d_in[7];
    float* out = (float*)d_out;                      // (32,512,1,1) fp32

    float* posm   = (float*)d_ws;          // 512 floats
    float* pooled = posm + 512;            // 16384 floats (offset 2 KiB, 16B-aligned)

    pos_mean_kernel<<<1, 512, 0, stream>>>(pos, posm);
    pool_kernel<<<4096, 256, 0, stream>>>(x, posm, pooled);
    matmul_bn_kernel<<<2048, 256, 0, stream>>>(pooled, conv_w, conv_b,
                                               bn_gamma, bn_beta, bn_mean, bn_var,
                                               out);
}